// Round 20
// baseline (377.695 us; speedup 1.0000x reference)
//
#include <hip/hip_runtime.h>
#include <hip/hip_bf16.h>
#include <stdint.h>

#define NROWS 32768   // 32*32*32
#define NCODE 4096
#define CDIM  256
#define KDIM  1024
#define NSLOT 96
#define MARGIN 1.0f

typedef __attribute__((ext_vector_type(8))) short bf16x8;
typedef __attribute__((ext_vector_type(4))) float f32x4;

static __device__ __forceinline__ unsigned f2ord(float f) {
    unsigned b = __float_as_uint(f);
    return (b & 0x80000000u) ? ~b : (b | 0x80000000u);
}
static __device__ __forceinline__ float ord2f(unsigned u) {
    unsigned b = (u & 0x80000000u) ? (u ^ 0x80000000u) : ~u;
    return __uint_as_float(b);
}
static __device__ __forceinline__ unsigned short to_bf16(float f) {
    __hip_bfloat16 h = __float2bfloat16(f);
    return *(unsigned short*)&h;
}

// ---------------- kernel 1: FUSED prep (r19, unchanged) ---------------------
// Blocks [0,256):   e = cb @ pw^T + pb (fp32 exact) + eb (bf16) + en4 partials
// Blocks [256,2304): z -> bf16 zb, zero cnt
extern "C" __global__ __launch_bounds__(256)
void k_prep(const float* __restrict__ cb, const float* __restrict__ pw,
            const float* __restrict__ pb, const float* __restrict__ z,
            float* __restrict__ e, unsigned short* __restrict__ eb,
            float* __restrict__ en4, unsigned short* __restrict__ zb,
            unsigned* __restrict__ cnt)
{
    __shared__ __align__(16) float As[32][68];
    __shared__ __align__(16) float Bs[32][68];
    const int blk = blockIdx.x;
    const int tid = threadIdx.x;

    if (blk >= 256) {                 // ---- cvtz branch ----
        size_t i = (size_t)(blk - 256) * 256 + tid;   // 16 floats / thread
        if (i < NROWS) cnt[i] = 0u;
        const float4* src = (const float4*)(z + i * 16);
        unsigned short o[16];
#pragma unroll
        for (int q = 0; q < 4; ++q) {
            float4 v = src[q];
            o[q * 4 + 0] = to_bf16(v.x); o[q * 4 + 1] = to_bf16(v.y);
            o[q * 4 + 2] = to_bf16(v.z); o[q * 4 + 3] = to_bf16(v.w);
        }
        *(uint4*)(zb + i * 16)     = *(const uint4*)&o[0];
        *(uint4*)(zb + i * 16 + 8) = *(const uint4*)&o[8];
        return;
    }

    // ---- proj branch ----
    const int tx = tid & 15, ty = tid >> 4;
    const int bm = blk >> 2;          // 0..63
    const int bn = blk & 3;           // 0..3
    float acc[4][4] = {};

    float4 pva[2], pvb[2];
    auto issueP = [&](int k0) {
#pragma unroll
        for (int i = 0; i < 2; ++i) {
            int idx = tid + i * 256;
            int row = idx >> 3;
            int kg  = (idx & 7) << 2;
            pva[i] = *(const float4*)(cb + (size_t)(bm * 64 + row) * KDIM + k0 + kg);
            pvb[i] = *(const float4*)(pw + (size_t)(bn * 64 + row) * KDIM + k0 + kg);
        }
    };

    issueP(0);
    for (int k0 = 0; k0 < KDIM; k0 += 32) {
#pragma unroll
        for (int i = 0; i < 2; ++i) {          // commit regs -> LDS (transpose)
            int idx = tid + i * 256;
            int row = idx >> 3;
            int kg  = (idx & 7) << 2;
            As[kg + 0][row] = pva[i].x; As[kg + 1][row] = pva[i].y;
            As[kg + 2][row] = pva[i].z; As[kg + 3][row] = pva[i].w;
            Bs[kg + 0][row] = pvb[i].x; Bs[kg + 1][row] = pvb[i].y;
            Bs[kg + 2][row] = pvb[i].z; Bs[kg + 3][row] = pvb[i].w;
        }
        __syncthreads();
        if (k0 + 32 < KDIM) issueP(k0 + 32);   // overlap with compute below
#pragma unroll
        for (int k = 0; k < 32; ++k) {
            float4 a = *(const float4*)&As[k][ty * 4];
            float4 b = *(const float4*)&Bs[k][tx * 4];
            float av[4] = {a.x, a.y, a.z, a.w};
            float bv[4] = {b.x, b.y, b.z, b.w};
#pragma unroll
            for (int i = 0; i < 4; ++i)
#pragma unroll
                for (int j = 0; j < 4; ++j)
                    acc[i][j] = fmaf(av[i], bv[j], acc[i][j]);
        }
        __syncthreads();
    }
    const int col0 = bn * 64 + tx * 4;
    float4 bias = *(const float4*)(pb + col0);
    float bb[4] = {bias.x, bias.y, bias.z, bias.w};
#pragma unroll
    for (int i = 0; i < 4; ++i) {
        int row = bm * 64 + ty * 4 + i;
        float o[4];
#pragma unroll
        for (int j = 0; j < 4; ++j) o[j] = acc[i][j] + bb[j];
        *(float4*)(e + (size_t)row * CDIM + col0) = make_float4(o[0], o[1], o[2], o[3]);
        ushort4 ob;
        ob.x = to_bf16(o[0]); ob.y = to_bf16(o[1]);
        ob.z = to_bf16(o[2]); ob.w = to_bf16(o[3]);
        *(ushort4*)(eb + (size_t)row * CDIM + col0) = ob;
        // partial ||e_row||^2 over this block's 64 dims (deterministic)
        float ns = o[0] * o[0] + o[1] * o[1] + o[2] * o[2] + o[3] * o[3];
#pragma unroll
        for (int off = 1; off < 16; off <<= 1) ns += __shfl_xor(ns, off);
        if (tx == 0) en4[bn * NCODE + row] = ns;
    }
}

// ---------------- kernel 2: bf16 MFMA score + block argmin + candidates -----
// r17/r19 structure (best measured) + T5 s_setprio around the ds_read+MFMA
// cluster.  The K-quarter stagger gives the 4 resident blocks/CU different
// phases (one staging while three compute), so raising compute-wave priority
// lets the MFMA pipe pre-empt stage-wave issue traffic (m224-conditional).
extern "C" __global__ __launch_bounds__(256, 4)
void k_dist(const unsigned short* __restrict__ zb, const unsigned short* __restrict__ eb,
            const float* __restrict__ en4, unsigned* __restrict__ cnt,
            unsigned* __restrict__ cand)
{
    __shared__ __align__(16) char lds[32768];     // As 16KB | Bs 16KB
    __shared__ unsigned rowmin[128];
    const int tid  = threadIdx.x;
    const int wave = tid >> 6, lane = tid & 63;
    const int bC = blockIdx.x, bR = blockIdx.y;   // grid (32, 256), bC fast
    const int wr = wave >> 1, wc = wave & 1;      // 2x2 waves, 64x64 out each
    const int fr = lane & 15;                     // A row / B col within frag
    const int kg = (lane >> 4) << 3;              // k sub-offset: 0,8,16,24
    const int qs = bC & 3;                        // per-block quarter stagger
    if (tid < 128) rowmin[tid] = 0xFFFFFFFFu;

    char* As = lds;
    char* Bs = lds + 16384;
    const char* gz = (const char*)zb + (size_t)bR * 128 * 512;  // row = 512B
    const char* ge = (const char*)eb + (size_t)bC * 128 * 512;

    // epilogue constants prefetched early (4-partial sum, deterministic)
    const int colg0 = bC * 128 + wc * 64;
    float env[4];
#pragma unroll
    for (int ni = 0; ni < 4; ++ni) {
        int c = colg0 + ni * 16 + fr;
        env[ni] = en4[c] + en4[NCODE + c] + en4[2 * NCODE + c] + en4[3 * NCODE + c];
    }

    f32x4 acc[4][4] = {};

    for (int qi = 0; qi < 4; ++qi) {              // staggered K quarters
        const int q = (qs + qi) & 3;              // k in [q*64, q*64+64)
#pragma unroll
        for (int i = 0; i < 4; ++i) {
            int chunk = tid + i * 256;            // [0,1024) 16B chunks
            int r  = chunk >> 3;                  // LDS/global row
            int wb = (chunk & 7) << 4;            // linear byte in 128B row
            int sw = wb ^ ((r & 7) << 4);         // inverse-swizzled source
            const char* gA = gz + (size_t)r * 512 + q * 128 + sw;
            const char* gB = ge + (size_t)r * 512 + q * 128 + sw;
            char* lA = As + i * 4096 + wave * 1024;   // wave-uniform base
            char* lB = Bs + i * 4096 + wave * 1024;
            __builtin_amdgcn_global_load_lds(
                (const __attribute__((address_space(1))) unsigned int*)gA,
                (__attribute__((address_space(3))) unsigned int*)lA, 16, 0, 0);
            __builtin_amdgcn_global_load_lds(
                (const __attribute__((address_space(1))) unsigned int*)gB,
                (__attribute__((address_space(3))) unsigned int*)lB, 16, 0, 0);
        }
        __syncthreads();   // drains vmcnt(0) before s_barrier
        __builtin_amdgcn_s_setprio(1);            // T5: favor compute waves
#pragma unroll
        for (int ks = 0; ks < 2; ++ks) {
            const int kb = (ks * 32 + kg) * 2;    // byte offset in 128B row
            bf16x8 a[4], b[4];
#pragma unroll
            for (int mi = 0; mi < 4; ++mi) {
                int row = wr * 64 + mi * 16 + fr;
                a[mi] = *(const bf16x8*)(As + row * 128 + (kb ^ ((row & 7) << 4)));
            }
#pragma unroll
            for (int ni = 0; ni < 4; ++ni) {
                int row = wc * 64 + ni * 16 + fr;
                b[ni] = *(const bf16x8*)(Bs + row * 128 + (kb ^ ((row & 7) << 4)));
            }
#pragma unroll
            for (int mi = 0; mi < 4; ++mi)
#pragma unroll
                for (int ni = 0; ni < 4; ++ni)
                    acc[mi][ni] = __builtin_amdgcn_mfma_f32_16x16x32_bf16(
                        a[mi], b[ni], acc[mi][ni], 0, 0, 0);
        }
        __builtin_amdgcn_s_setprio(0);
        __syncthreads();
    }

    // ---- epilogue: d~ = en[col] - 2*s ; block-local row minima ----
#pragma unroll
    for (int mi = 0; mi < 4; ++mi)
#pragma unroll
        for (int ni = 0; ni < 4; ++ni)
#pragma unroll
            for (int j = 0; j < 4; ++j)
                acc[mi][ni][j] = fmaf(-2.0f, acc[mi][ni][j], env[ni]);

#pragma unroll
    for (int mi = 0; mi < 4; ++mi) {
#pragma unroll
        for (int j = 0; j < 4; ++j) {
            unsigned best = 0xFFFFFFFFu;
#pragma unroll
            for (int ni = 0; ni < 4; ++ni) {
                unsigned o = f2ord(acc[mi][ni][j]);
                best = o < best ? o : best;
            }
#pragma unroll
            for (int off = 8; off >= 1; off >>= 1) {
                unsigned o = __shfl_xor(best, off);
                best = o < best ? o : best;
            }
            if (fr == 0) {
                int rl = wr * 64 + mi * 16 + ((lane >> 4) << 2) + j;
                atomicMin(&rowmin[rl], best);
            }
        }
    }
    __syncthreads();

    // ---- emission: every col within MARGIN of block-local row min.
    //      NaN-safe: !(x > thr) is TRUE for NaN -> mass-emit -> fallback.
#pragma unroll
    for (int mi = 0; mi < 4; ++mi) {
#pragma unroll
        for (int j = 0; j < 4; ++j) {
            int rl = wr * 64 + mi * 16 + ((lane >> 4) << 2) + j;
            float thr = ord2f(rowmin[rl]) + MARGIN;
#pragma unroll
            for (int ni = 0; ni < 4; ++ni) {
                if (!(acc[mi][ni][j] > thr)) {
                    int rg = bR * 128 + rl;
                    unsigned slot = atomicAdd(&cnt[rg], 1u);
                    if (slot < NSLOT)
                        cand[(size_t)rg * NSLOT + slot] =
                            (unsigned)(colg0 + ni * 16 + fr);
                }
            }
        }
    }
}

// ---------------- kernel 3: exact re-rank, 8 candidates per iteration -------
// Two independent eval chains (colA=i+g, colB=i+4+g) interleaved for 2x
// memory-level parallelism; lexicographic (d2,col) merge everywhere (colA <
// colB when both valid, so A wins ties -> exact argmin semantics preserved).
extern "C" __global__ __launch_bounds__(256)
void k_rerank(const float* __restrict__ z, const float* __restrict__ e,
              const float* __restrict__ en4, const unsigned* __restrict__ cnt,
              const unsigned* __restrict__ cand, unsigned* __restrict__ outidx)
{
    int row  = blockIdx.x * 4 + (threadIdx.x >> 6);
    int lane = threadIdx.x & 63;
    int g    = lane >> 4;           // candidate group 0..3
    int sl   = lane & 15;           // sub-lane: dims [sl*16, sl*16+16)
    const float* zp = z + (size_t)row * CDIM + sl * 16;
    float4 zv[4];
#pragma unroll
    for (int t = 0; t < 4; ++t) zv[t] = *(const float4*)(zp + t * 4);
    unsigned n = cnt[row];
    double best_d2 = 1e300;
    unsigned best_col = 0u;

    auto enof = [&](unsigned col) -> float {
        return en4[col] + en4[NCODE + col] + en4[2 * NCODE + col]
             + en4[3 * NCODE + col];
    };

    auto eval8 = [&](unsigned colA, bool vA, unsigned colB, bool vB) {
        const float* epA = e + (size_t)colA * CDIM + sl * 16;
        const float* epB = e + (size_t)colB * CDIM + sl * 16;
        double dA = 0.0, dB = 0.0;
#pragma unroll
        for (int t = 0; t < 4; ++t) {           // interleaved independent loads
            float4 evA = *(const float4*)(epA + t * 4);
            float4 evB = *(const float4*)(epB + t * 4);
            dA += (double)zv[t].x * evA.x + (double)zv[t].y * evA.y
                + (double)zv[t].z * evA.z + (double)zv[t].w * evA.w;
            dB += (double)zv[t].x * evB.x + (double)zv[t].y * evB.y
                + (double)zv[t].z * evB.z + (double)zv[t].w * evB.w;
        }
#pragma unroll
        for (int off = 1; off < 16; off <<= 1) {
            dA += __shfl_xor(dA, off);
            dB += __shfl_xor(dB, off);
        }
        double d2A = vA ? ((double)enof(colA) - 2.0 * dA) : 1e300;
        double d2B = vB ? ((double)enof(colB) - 2.0 * dB) : 1e300;
        double d2; unsigned col;
        if (d2B < d2A || (d2B == d2A && colB < colA)) { d2 = d2B; col = colB; }
        else                                          { d2 = d2A; col = colA; }
#pragma unroll
        for (int off = 16; off <= 32; off <<= 1) {
            double od2    = __shfl_xor(d2, off);
            unsigned ocol = (unsigned)__shfl_xor((int)col, off);
            if (od2 < d2 || (od2 == d2 && ocol < col)) { d2 = od2; col = ocol; }
        }
        if (d2 < best_d2 || (d2 == best_d2 && col < best_col)) {
            best_d2 = d2; best_col = col;
        }
    };

    if (n >= 1u && n <= (unsigned)NSLOT) {
        for (unsigned i = 0; i < n; i += 8) {
            unsigned iA = i + (unsigned)g, iB = i + 4 + (unsigned)g;
            bool vA = iA < n, vB = iB < n;
            unsigned colA = vA ? (cand[(size_t)row * NSLOT + iA] & (NCODE - 1)) : 0u;
            unsigned colB = vB ? (cand[(size_t)row * NSLOT + iB] & (NCODE - 1)) : 0u;
            eval8(colA, vA, colB, vB);
        }
    } else {
        // exact full scan over all 4096 codes (safety net)
        for (unsigned c0 = 0; c0 < NCODE; c0 += 8)
            eval8(c0 + (unsigned)g, true, c0 + 4 + (unsigned)g, true);
    }
    if (lane == 0) outidx[row] = best_col;
}

// ---------------- kernel 4: zidx + quant gather (overwrites ALL of d_out) ---
extern "C" __global__ __launch_bounds__(256)
void k_out(const unsigned* __restrict__ outidx, const float* __restrict__ e,
           float* __restrict__ out)
{
    int row  = blockIdx.x * 4 + (threadIdx.x >> 6);
    int lane = threadIdx.x & 63;
    unsigned idx = outidx[row] & (NCODE - 1);
    if (lane == 0) out[row] = (float)idx;
    float4 v = *(const float4*)(e + (size_t)idx * CDIM + lane * 4);
    *(float4*)(out + NROWS + (size_t)row * CDIM + lane * 4) = v;
}

extern "C" void kernel_launch(void* const* d_in, const int* in_sizes, int n_in,
                              void* d_out, int out_size, void* d_ws, size_t ws_size,
                              hipStream_t stream)
{
    const float* encode = (const float*)d_in[0];   // 32768 x 256
    const float* cb     = (const float*)d_in[1];   // 4096 x 1024
    const float* pw     = (const float*)d_in[2];   // 256 x 1024
    const float* pb     = (const float*)d_in[3];   // 256
    float* out = (float*)d_out;

    // ws: everything later kernels read while d_out is being rewritten.
    // 4.31 MiB total -- within the r5-proven footprint.
    char* ws = (char*)d_ws;
    float*    e      = (float*)(ws);                                  // 4 MiB
    float*    en4    = (float*)(ws + (4u << 20));                     // 64 KiB
    unsigned* cnt    = (unsigned*)(ws + (4u << 20) + (64u << 10));    // 128 KiB
    unsigned* outidx = (unsigned*)(ws + (4u << 20) + (192u << 10));   // 128 KiB

    // Big transients in d_out's quant region (scratch until k_out's final
    // full overwrite; nothing reads them after k_rerank).
    char* S = (char*)(out + NROWS);
    unsigned short* zb   = (unsigned short*)(S);               // 16 MiB
    unsigned short* eb   = (unsigned short*)(S + (16u << 20)); // 2 MiB
    unsigned*       cand = (unsigned*)(S + (18u << 20));       // 12 MiB (ends 30 MiB)

    k_prep  <<<dim3(2304),    256, 0, stream>>>(cb, pw, pb, encode,
                                                e, eb, en4, zb, cnt);
    k_dist  <<<dim3(32, 256), 256, 0, stream>>>(zb, eb, en4, cnt, cand);
    k_rerank<<<dim3(8192),    256, 0, stream>>>(encode, e, en4, cnt, cand, outidx);
    k_out   <<<dim3(8192),    256, 0, stream>>>(outidx, e, out);
}

// Round 21
// 365.200 us; speedup vs baseline: 1.0342x; 1.0342x over previous
//
#include <hip/hip_runtime.h>
#include <hip/hip_bf16.h>
#include <stdint.h>

#define NROWS 32768   // 32*32*32
#define NCODE 4096
#define CDIM  256
#define KDIM  1024
#define NSLOT 96
#define MARGIN 1.0f

typedef __attribute__((ext_vector_type(8))) short bf16x8;
typedef __attribute__((ext_vector_type(4))) float f32x4;

static __device__ __forceinline__ unsigned f2ord(float f) {
    unsigned b = __float_as_uint(f);
    return (b & 0x80000000u) ? ~b : (b | 0x80000000u);
}
static __device__ __forceinline__ float ord2f(unsigned u) {
    unsigned b = (u & 0x80000000u) ? (u ^ 0x80000000u) : ~u;
    return __uint_as_float(b);
}
static __device__ __forceinline__ unsigned short to_bf16(float f) {
    __hip_bfloat16 h = __float2bfloat16(f);
    return *(unsigned short*)&h;
}

// ---------------- kernel 1: FUSED prep --------------------------------------
// Blocks [0,256):   e = cb @ pw^T + pb (fp32 exact) + eb (bf16) + en4 partials
// Blocks [256,2304): z -> bf16 zb, zero cnt
extern "C" __global__ __launch_bounds__(256)
void k_prep(const float* __restrict__ cb, const float* __restrict__ pw,
            const float* __restrict__ pb, const float* __restrict__ z,
            float* __restrict__ e, unsigned short* __restrict__ eb,
            float* __restrict__ en4, unsigned short* __restrict__ zb,
            unsigned* __restrict__ cnt)
{
    __shared__ __align__(16) float As[32][68];
    __shared__ __align__(16) float Bs[32][68];
    const int blk = blockIdx.x;
    const int tid = threadIdx.x;

    if (blk >= 256) {                 // ---- cvtz branch ----
        size_t i = (size_t)(blk - 256) * 256 + tid;   // 16 floats / thread
        if (i < NROWS) cnt[i] = 0u;
        const float4* src = (const float4*)(z + i * 16);
        unsigned short o[16];
#pragma unroll
        for (int q = 0; q < 4; ++q) {
            float4 v = src[q];
            o[q * 4 + 0] = to_bf16(v.x); o[q * 4 + 1] = to_bf16(v.y);
            o[q * 4 + 2] = to_bf16(v.z); o[q * 4 + 3] = to_bf16(v.w);
        }
        *(uint4*)(zb + i * 16)     = *(const uint4*)&o[0];
        *(uint4*)(zb + i * 16 + 8) = *(const uint4*)&o[8];
        return;
    }

    // ---- proj branch ----
    const int tx = tid & 15, ty = tid >> 4;
    const int bm = blk >> 2;          // 0..63
    const int bn = blk & 3;           // 0..3
    float acc[4][4] = {};

    float4 pva[2], pvb[2];
    auto issueP = [&](int k0) {
#pragma unroll
        for (int i = 0; i < 2; ++i) {
            int idx = tid + i * 256;
            int row = idx >> 3;
            int kg  = (idx & 7) << 2;
            pva[i] = *(const float4*)(cb + (size_t)(bm * 64 + row) * KDIM + k0 + kg);
            pvb[i] = *(const float4*)(pw + (size_t)(bn * 64 + row) * KDIM + k0 + kg);
        }
    };

    issueP(0);
    for (int k0 = 0; k0 < KDIM; k0 += 32) {
#pragma unroll
        for (int i = 0; i < 2; ++i) {          // commit regs -> LDS (transpose)
            int idx = tid + i * 256;
            int row = idx >> 3;
            int kg  = (idx & 7) << 2;
            As[kg + 0][row] = pva[i].x; As[kg + 1][row] = pva[i].y;
            As[kg + 2][row] = pva[i].z; As[kg + 3][row] = pva[i].w;
            Bs[kg + 0][row] = pvb[i].x; Bs[kg + 1][row] = pvb[i].y;
            Bs[kg + 2][row] = pvb[i].z; Bs[kg + 3][row] = pvb[i].w;
        }
        __syncthreads();
        if (k0 + 32 < KDIM) issueP(k0 + 32);   // overlap with compute below
#pragma unroll
        for (int k = 0; k < 32; ++k) {
            float4 a = *(const float4*)&As[k][ty * 4];
            float4 b = *(const float4*)&Bs[k][tx * 4];
            float av[4] = {a.x, a.y, a.z, a.w};
            float bv[4] = {b.x, b.y, b.z, b.w};
#pragma unroll
            for (int i = 0; i < 4; ++i)
#pragma unroll
                for (int j = 0; j < 4; ++j)
                    acc[i][j] = fmaf(av[i], bv[j], acc[i][j]);
        }
        __syncthreads();
    }
    const int col0 = bn * 64 + tx * 4;
    float4 bias = *(const float4*)(pb + col0);
    float bb[4] = {bias.x, bias.y, bias.z, bias.w};
#pragma unroll
    for (int i = 0; i < 4; ++i) {
        int row = bm * 64 + ty * 4 + i;
        float o[4];
#pragma unroll
        for (int j = 0; j < 4; ++j) o[j] = acc[i][j] + bb[j];
        *(float4*)(e + (size_t)row * CDIM + col0) = make_float4(o[0], o[1], o[2], o[3]);
        ushort4 ob;
        ob.x = to_bf16(o[0]); ob.y = to_bf16(o[1]);
        ob.z = to_bf16(o[2]); ob.w = to_bf16(o[3]);
        *(ushort4*)(eb + (size_t)row * CDIM + col0) = ob;
        // partial ||e_row||^2 over this block's 64 dims (deterministic)
        float ns = o[0] * o[0] + o[1] * o[1] + o[2] * o[2] + o[3] * o[3];
#pragma unroll
        for (int off = 1; off < 16; off <<= 1) ns += __shfl_xor(ns, off);
        if (tx == 0) en4[bn * NCODE + row] = ns;
    }
}

// ---------------- kernel 2: bf16 MFMA score + block argmin + candidates -----
// Best-measured structure (r17/r19, ~226 us): 128x128 tile, grid (32,256)
// bC-fast, 33,280B LDS, 4 blk/CU, global_load_lds width-16 (linear dest +
// inverse-swizzled source, rule #21), vmcnt(0)-drain __syncthreads, K-quarter
// stagger (breaks cross-block phase-lock, +6us).  env = inline en4 sum.
extern "C" __global__ __launch_bounds__(256, 4)
void k_dist(const unsigned short* __restrict__ zb, const unsigned short* __restrict__ eb,
            const float* __restrict__ en4, unsigned* __restrict__ cnt,
            unsigned* __restrict__ cand)
{
    __shared__ __align__(16) char lds[32768];     // As 16KB | Bs 16KB
    __shared__ unsigned rowmin[128];
    const int tid  = threadIdx.x;
    const int wave = tid >> 6, lane = tid & 63;
    const int bC = blockIdx.x, bR = blockIdx.y;   // grid (32, 256), bC fast
    const int wr = wave >> 1, wc = wave & 1;      // 2x2 waves, 64x64 out each
    const int fr = lane & 15;                     // A row / B col within frag
    const int kg = (lane >> 4) << 3;              // k sub-offset: 0,8,16,24
    const int qs = bC & 3;                        // per-block quarter stagger
    if (tid < 128) rowmin[tid] = 0xFFFFFFFFu;

    char* As = lds;
    char* Bs = lds + 16384;
    const char* gz = (const char*)zb + (size_t)bR * 128 * 512;  // row = 512B
    const char* ge = (const char*)eb + (size_t)bC * 128 * 512;

    // epilogue constants prefetched early (4-partial sum, deterministic)
    const int colg0 = bC * 128 + wc * 64;
    float env[4];
#pragma unroll
    for (int ni = 0; ni < 4; ++ni) {
        int c = colg0 + ni * 16 + fr;
        env[ni] = en4[c] + en4[NCODE + c] + en4[2 * NCODE + c] + en4[3 * NCODE + c];
    }

    f32x4 acc[4][4] = {};

    for (int qi = 0; qi < 4; ++qi) {              // staggered K quarters
        const int q = (qs + qi) & 3;              // k in [q*64, q*64+64)
#pragma unroll
        for (int i = 0; i < 4; ++i) {
            int chunk = tid + i * 256;            // [0,1024) 16B chunks
            int r  = chunk >> 3;                  // LDS/global row
            int wb = (chunk & 7) << 4;            // linear byte in 128B row
            int sw = wb ^ ((r & 7) << 4);         // inverse-swizzled source
            const char* gA = gz + (size_t)r * 512 + q * 128 + sw;
            const char* gB = ge + (size_t)r * 512 + q * 128 + sw;
            char* lA = As + i * 4096 + wave * 1024;   // wave-uniform base
            char* lB = Bs + i * 4096 + wave * 1024;
            __builtin_amdgcn_global_load_lds(
                (const __attribute__((address_space(1))) unsigned int*)gA,
                (__attribute__((address_space(3))) unsigned int*)lA, 16, 0, 0);
            __builtin_amdgcn_global_load_lds(
                (const __attribute__((address_space(1))) unsigned int*)gB,
                (__attribute__((address_space(3))) unsigned int*)lB, 16, 0, 0);
        }
        __syncthreads();   // drains vmcnt(0) before s_barrier
#pragma unroll
        for (int ks = 0; ks < 2; ++ks) {
            const int kb = (ks * 32 + kg) * 2;    // byte offset in 128B row
            bf16x8 a[4], b[4];
#pragma unroll
            for (int mi = 0; mi < 4; ++mi) {
                int row = wr * 64 + mi * 16 + fr;
                a[mi] = *(const bf16x8*)(As + row * 128 + (kb ^ ((row & 7) << 4)));
            }
#pragma unroll
            for (int ni = 0; ni < 4; ++ni) {
                int row = wc * 64 + ni * 16 + fr;
                b[ni] = *(const bf16x8*)(Bs + row * 128 + (kb ^ ((row & 7) << 4)));
            }
#pragma unroll
            for (int mi = 0; mi < 4; ++mi)
#pragma unroll
                for (int ni = 0; ni < 4; ++ni)
                    acc[mi][ni] = __builtin_amdgcn_mfma_f32_16x16x32_bf16(
                        a[mi], b[ni], acc[mi][ni], 0, 0, 0);
        }
        __syncthreads();
    }

    // ---- epilogue: d~ = en[col] - 2*s ; block-local row minima ----
#pragma unroll
    for (int mi = 0; mi < 4; ++mi)
#pragma unroll
        for (int ni = 0; ni < 4; ++ni)
#pragma unroll
            for (int j = 0; j < 4; ++j)
                acc[mi][ni][j] = fmaf(-2.0f, acc[mi][ni][j], env[ni]);

#pragma unroll
    for (int mi = 0; mi < 4; ++mi) {
#pragma unroll
        for (int j = 0; j < 4; ++j) {
            unsigned best = 0xFFFFFFFFu;
#pragma unroll
            for (int ni = 0; ni < 4; ++ni) {
                unsigned o = f2ord(acc[mi][ni][j]);
                best = o < best ? o : best;
            }
#pragma unroll
            for (int off = 8; off >= 1; off >>= 1) {
                unsigned o = __shfl_xor(best, off);
                best = o < best ? o : best;
            }
            if (fr == 0) {
                int rl = wr * 64 + mi * 16 + ((lane >> 4) << 2) + j;
                atomicMin(&rowmin[rl], best);
            }
        }
    }
    __syncthreads();

    // ---- emission: every col within MARGIN of block-local row min.
    //      NaN-safe: !(x > thr) is TRUE for NaN -> mass-emit -> fallback.
#pragma unroll
    for (int mi = 0; mi < 4; ++mi) {
#pragma unroll
        for (int j = 0; j < 4; ++j) {
            int rl = wr * 64 + mi * 16 + ((lane >> 4) << 2) + j;
            float thr = ord2f(rowmin[rl]) + MARGIN;
#pragma unroll
            for (int ni = 0; ni < 4; ++ni) {
                if (!(acc[mi][ni][j] > thr)) {
                    int rg = bR * 128 + rl;
                    unsigned slot = atomicAdd(&cnt[rg], 1u);
                    if (slot < NSLOT)
                        cand[(size_t)rg * NSLOT + slot] =
                            (unsigned)(colg0 + ni * 16 + fr);
                }
            }
        }
    }
}

// ---------------- kernel 3: exact re-rank, 4 candidates in parallel ---------
extern "C" __global__ __launch_bounds__(256)
void k_rerank(const float* __restrict__ z, const float* __restrict__ e,
              const float* __restrict__ en4, const unsigned* __restrict__ cnt,
              const unsigned* __restrict__ cand, unsigned* __restrict__ outidx)
{
    int row  = blockIdx.x * 4 + (threadIdx.x >> 6);
    int lane = threadIdx.x & 63;
    int g    = lane >> 4;           // which of the 4 parallel candidates
    int sl   = lane & 15;           // sub-lane: dims [sl*16, sl*16+16)
    const float* zp = z + (size_t)row * CDIM + sl * 16;
    float4 zv[4];
#pragma unroll
    for (int t = 0; t < 4; ++t) zv[t] = *(const float4*)(zp + t * 4);
    unsigned n = cnt[row];
    double best_d2 = 1e300;
    unsigned best_col = 0u;

    auto eval4 = [&](unsigned col, bool valid) {
        const float* ep = e + (size_t)col * CDIM + sl * 16;
        double dot = 0.0;
#pragma unroll
        for (int t = 0; t < 4; ++t) {
            float4 ev = *(const float4*)(ep + t * 4);
            dot += (double)zv[t].x * ev.x + (double)zv[t].y * ev.y
                 + (double)zv[t].z * ev.z + (double)zv[t].w * ev.w;
        }
#pragma unroll
        for (int off = 1; off < 16; off <<= 1) dot += __shfl_xor(dot, off);
        float enc = en4[col] + en4[NCODE + col]
                  + en4[2 * NCODE + col] + en4[3 * NCODE + col];
        double d2 = valid ? ((double)enc - 2.0 * dot) : 1e300;
#pragma unroll
        for (int off = 16; off <= 32; off <<= 1) {
            double od2    = __shfl_xor(d2, off);
            unsigned ocol = (unsigned)__shfl_xor((int)col, off);
            if (od2 < d2 || (od2 == d2 && ocol < col)) { d2 = od2; col = ocol; }
        }
        if (d2 < best_d2 || (d2 == best_d2 && col < best_col)) {
            best_d2 = d2; best_col = col;
        }
    };

    if (n >= 1u && n <= (unsigned)NSLOT) {
        for (unsigned i = 0; i < n; i += 4) {
            unsigned ii = i + (unsigned)g;
            bool valid = ii < n;
            unsigned col = valid ? (cand[(size_t)row * NSLOT + ii] & (NCODE - 1)) : 0u;
            eval4(col, valid);
        }
    } else {
        for (unsigned c0 = 0; c0 < NCODE; c0 += 4)
            eval4(c0 + (unsigned)g, true);
    }
    if (lane == 0) outidx[row] = best_col;
}

// ---------------- kernel 4: zidx + quant gather (overwrites ALL of d_out) ---
extern "C" __global__ __launch_bounds__(256)
void k_out(const unsigned* __restrict__ outidx, const float* __restrict__ e,
           float* __restrict__ out)
{
    int row  = blockIdx.x * 4 + (threadIdx.x >> 6);
    int lane = threadIdx.x & 63;
    unsigned idx = outidx[row] & (NCODE - 1);
    if (lane == 0) out[row] = (float)idx;
    float4 v = *(const float4*)(e + (size_t)idx * CDIM + lane * 4);
    *(float4*)(out + NROWS + (size_t)row * CDIM + lane * 4) = v;
}

extern "C" void kernel_launch(void* const* d_in, const int* in_sizes, int n_in,
                              void* d_out, int out_size, void* d_ws, size_t ws_size,
                              hipStream_t stream)
{
    const float* encode = (const float*)d_in[0];   // 32768 x 256
    const float* cb     = (const float*)d_in[1];   // 4096 x 1024
    const float* pw     = (const float*)d_in[2];   // 256 x 1024
    const float* pb     = (const float*)d_in[3];   // 256
    float* out = (float*)d_out;

    // ws: everything later kernels read while d_out is being rewritten.
    // 4.31 MiB total -- within the r5-proven footprint.
    char* ws = (char*)d_ws;
    float*    e      = (float*)(ws);                                  // 4 MiB
    float*    en4    = (float*)(ws + (4u << 20));                     // 64 KiB
    unsigned* cnt    = (unsigned*)(ws + (4u << 20) + (64u << 10));    // 128 KiB
    unsigned* outidx = (unsigned*)(ws + (4u << 20) + (192u << 10));   // 128 KiB

    // Big transients in d_out's quant region (scratch until k_out's final
    // full overwrite; nothing reads them after k_rerank).
    char* S = (char*)(out + NROWS);
    unsigned short* zb   = (unsigned short*)(S);               // 16 MiB
    unsigned short* eb   = (unsigned short*)(S + (16u << 20)); // 2 MiB
    unsigned*       cand = (unsigned*)(S + (18u << 20));       // 12 MiB (ends 30 MiB)

    k_prep  <<<dim3(2304),    256, 0, stream>>>(cb, pw, pb, encode,
                                                e, eb, en4, zb, cnt);
    k_dist  <<<dim3(32, 256), 256, 0, stream>>>(zb, eb, en4, cnt, cand);
    k_rerank<<<dim3(8192),    256, 0, stream>>>(encode, e, en4, cnt, cand, outidx);
    k_out   <<<dim3(8192),    256, 0, stream>>>(outidx, e, out);
}